// Round 2
// baseline (18988.292 us; speedup 1.0000x reference)
//
#include <hip/hip_runtime.h>
#include <stdint.h>

// T=512, B=32, I=1024, H=1024, G=4H=4096
// out: [512][32][2048] fp32 then hf[32][1024], cf, hb, cb  (total 33685504 f32)

using short8 = __attribute__((ext_vector_type(8))) short;   // 8 bf16
using f32x4  = __attribute__((ext_vector_type(4))) float;
using f32x16 = __attribute__((ext_vector_type(16))) float;

typedef unsigned int uint;
typedef unsigned short ushort;

// ---------------- ws layout (bytes) ----------------
#define OFF_XB      0ull            // x as bf16: 16777216 * 2 = 33554432
#define OFF_WIH_F   33554432ull     // 4096*1024*2 = 8388608
#define OFF_WIH_B   41943040ull
#define OFF_WHH_F   50331648ull
#define OFF_WHH_B   58720256ull
#define OFF_BSUM_F  67108864ull     // 4096 * 4
#define OFF_BSUM_B  67125248ull
#define OFF_HBUF    67141632ull     // 2 dir * 2 parity * 32*1024 * 2B = 262144
#define OFF_CBUF    67403776ull     // 2 * 32*1024 * 4B = 262144
#define OFF_FLAGS   67665920ull     // 64 uints; dir0 flags[0..31], dir1 flags[32..63]
#define OFF_XG      67670016ull     // fp16 xg: 2 * csteps*32*4096*2

__device__ __forceinline__ ushort f2bf(float f) {
    uint u = __float_as_uint(f);
    u += 0x7fffu + ((u >> 16) & 1u);   // RNE
    return (ushort)(u >> 16);
}
__device__ __forceinline__ float sigmoidf_(float x) { return 1.0f / (1.0f + expf(-x)); }

// ---------------- prep: fp32 -> bf16 converts, bias sums, h0, flags ----------------
__global__ __launch_bounds__(256) void prep_kernel(
    const float* __restrict__ x,
    const float* __restrict__ wih_f, const float* __restrict__ whh_f,
    const float* __restrict__ bih_f, const float* __restrict__ bhh_f,
    const float* __restrict__ wih_b, const float* __restrict__ whh_b,
    const float* __restrict__ bih_b, const float* __restrict__ bhh_b,
    const float* __restrict__ h0f, const float* __restrict__ h0b,
    char* __restrict__ ws)
{
    int r = blockIdx.x * 256 + threadIdx.x;
    const int n_x = 16777216, n_w = 4194304;
    if (r < n_x) { ((ushort*)(ws + OFF_XB))[r] = f2bf(x[r]); return; }
    r -= n_x;
    if (r < n_w) { ((ushort*)(ws + OFF_WIH_F))[r] = f2bf(wih_f[r]); return; }
    r -= n_w;
    if (r < n_w) { ((ushort*)(ws + OFF_WIH_B))[r] = f2bf(wih_b[r]); return; }
    r -= n_w;
    if (r < n_w) { ((ushort*)(ws + OFF_WHH_F))[r] = f2bf(whh_f[r]); return; }
    r -= n_w;
    if (r < n_w) { ((ushort*)(ws + OFF_WHH_B))[r] = f2bf(whh_b[r]); return; }
    r -= n_w;
    if (r < 4096) { ((float*)(ws + OFF_BSUM_F))[r] = bih_f[r] + bhh_f[r]; return; }
    r -= 4096;
    if (r < 4096) { ((float*)(ws + OFF_BSUM_B))[r] = bih_b[r] + bhh_b[r]; return; }
    r -= 4096;
    if (r < 32768) { ((ushort*)(ws + OFF_HBUF))[r] = f2bf(h0f[r]); return; }             // dir0,parity0
    r -= 32768;
    if (r < 32768) { ((ushort*)(ws + OFF_HBUF))[2 * 32768 + r] = f2bf(h0b[r]); return; } // dir1,parity0
    r -= 32768;
    if (r < 64) { ((uint*)(ws + OFF_FLAGS))[r] = 0u; return; }
}

// ---------------- xg GEMM: xg[slot*32+b][g] = sum_i x[t][b][i] * Wih[g][i] ----------------
__global__ __launch_bounds__(256) void gemm_xg(
    const ushort* __restrict__ xb,
    const ushort* __restrict__ wihf, const ushort* __restrict__ wihb,
    _Float16* __restrict__ xgf, _Float16* __restrict__ xgb,
    int s0)
{
    __shared__ ushort As[128 * 32];
    __shared__ ushort Bs[128 * 32];
    const int dir = blockIdx.z;
    const ushort* __restrict__ W = dir ? wihb : wihf;
    _Float16* __restrict__ xg = dir ? xgb : xgf;
    const int mBlk = blockIdx.x, nBlk = blockIdx.y;
    const int tid = threadIdx.x;
    const int w = tid >> 6, l = tid & 63;
    const int q = l >> 4, ml = l & 15;

    f32x4 acc[4][4];
    const f32x4 zero = {0.f, 0.f, 0.f, 0.f};
#pragma unroll
    for (int i = 0; i < 4; ++i)
#pragma unroll
        for (int j = 0; j < 4; ++j) acc[i][j] = zero;

    for (int kb = 0; kb < 32; ++kb) {
#pragma unroll
        for (int it = 0; it < 2; ++it) {
            int idx = tid + 256 * it;           // 0..511
            int rl = idx >> 2, kc = idx & 3;
            int gr = mBlk * 128 + rl;           // row in slot-space
            int slot = gr >> 5, bb = gr & 31;
            int t = dir ? (511 - s0 - slot) : (s0 + slot);
            const ushort* ga = xb + (size_t)(t * 32 + bb) * 1024 + kb * 32 + kc * 8;
            *(short8*)(As + idx * 8) = *(const short8*)ga;
            int colg = nBlk * 128 + rl;
            const ushort* gbp = W + (size_t)colg * 1024 + kb * 32 + kc * 8;
            *(short8*)(Bs + idx * 8) = *(const short8*)gbp;
        }
        __syncthreads();
        short8 af[4], bfr[4];
#pragma unroll
        for (int i = 0; i < 4; ++i)
            af[i] = *(const short8*)(As + ((w & 1) * 64 + i * 16 + ml) * 32 + q * 8);
#pragma unroll
        for (int j = 0; j < 4; ++j)
            bfr[j] = *(const short8*)(Bs + ((w >> 1) * 64 + j * 16 + ml) * 32 + q * 8);
#pragma unroll
        for (int i = 0; i < 4; ++i)
#pragma unroll
            for (int j = 0; j < 4; ++j)
                acc[i][j] = __builtin_amdgcn_mfma_f32_16x16x32_bf16(af[i], bfr[j], acc[i][j], 0, 0, 0);
        __syncthreads();
    }
#pragma unroll
    for (int i = 0; i < 4; ++i)
#pragma unroll
        for (int j = 0; j < 4; ++j)
#pragma unroll
            for (int rr = 0; rr < 4; ++rr) {
                int row = mBlk * 128 + (w & 1) * 64 + i * 16 + q * 4 + rr;
                int col = nBlk * 128 + (w >> 1) * 64 + j * 16 + ml;
                xg[(size_t)row * 4096 + col] = (_Float16)acc[i][j][rr];
            }
}

// ---------------- recurrence: cooperative, 64 blocks x 512 threads ----------------
// dir = bx&1, p = bx>>1 (0..31). Block owns h-cols [p*32,(p+1)*32) and gate cols
// {g*1024 + p*32 + r}. Wave w (0..7): gate nt=w&3, K-half kh=w>>2. B-frags (32 cols
// x 512 K) persist in 128 VGPRs/lane. Barrier = scattered per-block flags; staging
// loop IS the barrier: each wave spin-acquires its 4 producers' flags and pulls
// their 2KB h-slices into swizzled LDS as they arrive.
__global__ __launch_bounds__(512, 2) void rec_kernel(
    const ushort* __restrict__ whhf, const ushort* __restrict__ whhb,
    const _Float16* __restrict__ xgf, const _Float16* __restrict__ xgb,
    const float* __restrict__ bsumf, const float* __restrict__ bsumb,
    const float* __restrict__ c0f, const float* __restrict__ c0b,
    ushort* __restrict__ hbuf, float* __restrict__ cbuf,
    float* __restrict__ out, uint* __restrict__ flags,
    int s0, int csteps)
{
    __shared__ __align__(16) char lds_raw[65536];   // h-stage (64KB), overlaid by gate buf
    ushort* Hst = (ushort*)lds_raw;
    float*  gb  = (float*)lds_raw;

    const int bx = blockIdx.x;
    const int dir = bx & 1;
    const int p = bx >> 1;              // 0..31
    const int tid = threadIdx.x;
    const int w = tid >> 6;             // 0..7
    const int l = tid & 63;
    const int half = l >> 5;
    const int m32 = l & 31;
    const int nt = w & 3;               // gate index
    const int kh = w >> 2;              // K half

    const ushort* W = dir ? whhb : whhf;
    const _Float16* xg = dir ? xgb : xgf;
    const float* bsum = dir ? bsumb : bsumf;
    uint* fl = flags + dir * 32;

    // B-frag preload: col = nt*1024 + p*32 + m32, k = kh*512 + kk*16 + half*8 + j
    const ushort* wrow = W + ((size_t)(nt * 1024 + p * 32 + m32)) * 1024 + kh * 512 + half * 8;
    short8 bfrag[32];
#pragma unroll
    for (int kk = 0; kk < 32; ++kk)
        bfrag[kk] = *(const short8*)(wrow + kk * 16);

    // elementwise identity: (b, r) pairs: e = tid and tid+512
    const int bth = tid >> 5;           // 0..15
    const int r = tid & 31;
    const int hcol = p * 32 + r;
    const float bs0 = bsum[hcol], bs1 = bsum[1024 + hcol],
                bs2 = bsum[2048 + hcol], bs3 = bsum[3072 + hcol];
    float cc[2];
#pragma unroll
    for (int j = 0; j < 2; ++j) {
        const int b = bth + 16 * j;
        cc[j] = (s0 == 0) ? ((dir ? c0b : c0f)[b * 1024 + hcol])
                          : cbuf[dir * 32768 + b * 1024 + hcol];
    }

    for (int s = s0; s < s0 + csteps; ++s) {
        // ---- stage h^s (parity s&1) as producers arrive; this IS the barrier ----
        const ushort* hsrc = hbuf + (size_t)(dir * 2 + (s & 1)) * 32768;
#pragma unroll
        for (int i = 0; i < 4; ++i) {
            const int pc = w * 4 + i;
            for (;;) {
                uint v = __hip_atomic_load(fl + pc, __ATOMIC_ACQUIRE, __HIP_MEMORY_SCOPE_AGENT);
                if (v >= (uint)s) break;
                __builtin_amdgcn_s_sleep(2);
            }
            const int b = l >> 1;
            const int k0 = pc * 32 + (l & 1) * 16;
            const short8 d0 = *(const short8*)(hsrc + b * 1024 + k0);
            const short8 d1 = *(const short8*)(hsrc + b * 1024 + k0 + 8);
            const int ch0 = k0 >> 3;
            *(short8*)(Hst + b * 1024 + ((ch0 ^ (b & 7)) << 3)) = d0;
            *(short8*)(Hst + b * 1024 + (((ch0 + 1) ^ (b & 7)) << 3)) = d1;
        }
        __syncthreads();

        // ---- MFMA: gates[32, 32cols] partial over K-half, 2 indep acc chains ----
        f32x16 acce, acco;
#pragma unroll
        for (int i = 0; i < 16; ++i) { acce[i] = 0.f; acco[i] = 0.f; }
#pragma unroll
        for (int kk = 0; kk < 32; kk += 2) {
            const short8 a0 = *(const short8*)(Hst + m32 * 1024 +
                (((kh * 64 + kk * 2 + half) ^ (m32 & 7)) << 3));
            acce = __builtin_amdgcn_mfma_f32_32x32x16_bf16(a0, bfrag[kk], acce, 0, 0, 0);
            const short8 a1 = *(const short8*)(Hst + m32 * 1024 +
                (((kh * 64 + (kk + 1) * 2 + half) ^ (m32 & 7)) << 3));
            acco = __builtin_amdgcn_mfma_f32_32x32x16_bf16(a1, bfrag[kk + 1], acco, 0, 0, 0);
        }
        __syncthreads();   // all Hst reads done before gbuf overlay writes

        // ---- C-store: row=(reg&3)+8*(reg>>2)+4*half, col=m32 ----
#pragma unroll
        for (int reg = 0; reg < 16; ++reg) {
            const int row = (reg & 3) + 8 * (reg >> 2) + 4 * half;
            gb[kh * 4224 + row * 132 + nt * 32 + m32] = acce[reg] + acco[reg];
        }
        __syncthreads();

        // ---- elementwise LSTM update ----
        const int slot = s - s0;
        const int t = dir ? (511 - s) : s;
        ushort* hdst = hbuf + (size_t)(dir * 2 + ((s + 1) & 1)) * 32768;
        float hh[2];
#pragma unroll
        for (int j = 0; j < 2; ++j) {
            const int b = bth + 16 * j;
            const int gbase = b * 132 + r;
            const _Float16* xrow = xg + ((size_t)slot * 32 + b) * 4096 + hcol;
            float gi = gb[gbase]      + gb[4224 + gbase]      + bs0 + (float)xrow[0];
            float gf = gb[gbase + 32] + gb[4224 + gbase + 32] + bs1 + (float)xrow[1024];
            float gg = gb[gbase + 64] + gb[4224 + gbase + 64] + bs2 + (float)xrow[2048];
            float go = gb[gbase + 96] + gb[4224 + gbase + 96] + bs3 + (float)xrow[3072];
            float ii = sigmoidf_(gi), ff2 = sigmoidf_(gf), g2 = tanhf(gg), oo = sigmoidf_(go);
            cc[j] = ff2 * cc[j] + ii * g2;
            hh[j] = oo * tanhf(cc[j]);
            hdst[b * 1024 + hcol] = f2bf(hh[j]);
        }
        __threadfence();
        __syncthreads();
        if (tid == 0)
            __hip_atomic_store(fl + p, (uint)(s + 1), __ATOMIC_RELEASE, __HIP_MEMORY_SCOPE_AGENT);

        // ---- out stores (off the critical path) ----
#pragma unroll
        for (int j = 0; j < 2; ++j) {
            const int b = bth + 16 * j;
            out[(size_t)t * 65536 + b * 2048 + dir * 1024 + hcol] = hh[j];
            if (s == 511) {
                float* fin = out + 33554432 + dir * 65536;   // hf,cf then hb,cb
                fin[b * 1024 + hcol] = hh[j];
                fin[32768 + b * 1024 + hcol] = cc[j];
            }
        }
    }
#pragma unroll
    for (int j = 0; j < 2; ++j)
        cbuf[dir * 32768 + (bth + 16 * j) * 1024 + hcol] = cc[j];
}

// ---------------- host ----------------
extern "C" void kernel_launch(void* const* d_in, const int* in_sizes, int n_in,
                              void* d_out, int out_size, void* d_ws, size_t ws_size,
                              hipStream_t stream)
{
    const float* x     = (const float*)d_in[0];
    const float* h0f   = (const float*)d_in[1];
    const float* c0f   = (const float*)d_in[2];
    const float* h0b   = (const float*)d_in[3];
    const float* c0b   = (const float*)d_in[4];
    const float* wih_f = (const float*)d_in[5];
    const float* whh_f = (const float*)d_in[6];
    const float* bih_f = (const float*)d_in[7];
    const float* bhh_f = (const float*)d_in[8];
    const float* wih_b = (const float*)d_in[9];
    const float* whh_b = (const float*)d_in[10];
    const float* bih_b = (const float*)d_in[11];
    const float* bhh_b = (const float*)d_in[12];
    float* out = (float*)d_out;
    char* ws = (char*)d_ws;

    int csteps = 16;
    const int cands[6] = {512, 256, 128, 64, 32, 16};
    for (int i = 0; i < 6; ++i) {
        size_t need = OFF_XG + 2ull * (size_t)cands[i] * 262144ull;
        if (need <= ws_size) { csteps = cands[i]; break; }
    }

    prep_kernel<<<131361, 256, 0, stream>>>(x, wih_f, whh_f, bih_f, bhh_f,
                                            wih_b, whh_b, bih_b, bhh_b, h0f, h0b, ws);

    const ushort* xb    = (const ushort*)(ws + OFF_XB);
    const ushort* wihfb = (const ushort*)(ws + OFF_WIH_F);
    const ushort* wihbb = (const ushort*)(ws + OFF_WIH_B);
    const ushort* whhfb = (const ushort*)(ws + OFF_WHH_F);
    const ushort* whhbb = (const ushort*)(ws + OFF_WHH_B);
    const float*  bsf   = (const float*)(ws + OFF_BSUM_F);
    const float*  bsb   = (const float*)(ws + OFF_BSUM_B);
    ushort* hb          = (ushort*)(ws + OFF_HBUF);
    float*  cb          = (float*)(ws + OFF_CBUF);
    uint*   flagsp      = (uint*)(ws + OFF_FLAGS);
    _Float16* xgfp      = (_Float16*)(ws + OFF_XG);
    _Float16* xgbp      = (_Float16*)(ws + OFF_XG + (size_t)csteps * 262144ull);

    const int nchunks = 512 / csteps;
    for (int cidx = 0; cidx < nchunks; ++cidx) {
        int s0 = cidx * csteps;
        gemm_xg<<<dim3(csteps / 4, 32, 2), 256, 0, stream>>>(xb, wihfb, wihbb, xgfp, xgbp, s0);

        const ushort* a0 = whhfb; const ushort* a1 = whhbb;
        const _Float16* a2 = xgfp; const _Float16* a3 = xgbp;
        const float* a4 = bsf; const float* a5 = bsb;
        const float* a6 = c0f; const float* a7 = c0b;
        ushort* a8 = hb; float* a9 = cb; float* a10 = out; uint* a11 = flagsp;
        int a12 = s0, a13 = csteps;
        void* args[] = {&a0, &a1, &a2, &a3, &a4, &a5, &a6, &a7, &a8, &a9, &a10, &a11, &a12, &a13};
        hipLaunchCooperativeKernel((void*)rec_kernel, dim3(64), dim3(512), args, 0, stream);
    }
}

// Round 3
// 4393.019 us; speedup vs baseline: 4.3224x; 4.3224x over previous
//
#include <hip/hip_runtime.h>
#include <stdint.h>

// T=512, B=32, I=1024, H=1024, G=4H=4096
// out: [512][32][2048] fp32 then hf[32][1024], cf, hb, cb  (total 33685504 f32)

using short8 = __attribute__((ext_vector_type(8))) short;   // 8 bf16
using f32x4  = __attribute__((ext_vector_type(4))) float;
using f32x2  = __attribute__((ext_vector_type(2))) float;
using f32x16 = __attribute__((ext_vector_type(16))) float;
using h2f    = __attribute__((ext_vector_type(2))) _Float16;

typedef unsigned int uint;
typedef unsigned short ushort;
typedef unsigned long long ull;

// ---------------- ws layout (bytes) ----------------
#define OFF_XB      0ull            // x as bf16: 16777216 * 2 = 33554432
#define OFF_WIH_F   33554432ull     // 4096*1024*2 = 8388608
#define OFF_WIH_B   41943040ull
#define OFF_WHH_F   50331648ull
#define OFF_WHH_B   58720256ull
#define OFF_BSUM_F  67108864ull     // 4096 * 4
#define OFF_BSUM_B  67125248ull
#define OFF_HBUF    67141632ull     // 2 dir * 2 parity * 32*1024 * 2B = 262144
#define OFF_CBUF    67403776ull     // 2 * 32*1024 * 4B = 262144
#define OFF_FLAGS   67665920ull     // 64 uints; dir0 flags[0..31], dir1 flags[32..63]
#define OFF_XG      67670016ull     // fp16 xg: 2 * csteps*32*4096*2

__device__ __forceinline__ ushort f2bf(float f) {
    uint u = __float_as_uint(f);
    u += 0x7fffu + ((u >> 16) & 1u);   // RNE
    return (ushort)(u >> 16);
}
__device__ __forceinline__ float sigmoidf_(float x) { return 1.0f / (1.0f + expf(-x)); }

// ---------------- prep: fp32 -> bf16 converts, bias sums, h0, flags ----------------
__global__ __launch_bounds__(256) void prep_kernel(
    const float* __restrict__ x,
    const float* __restrict__ wih_f, const float* __restrict__ whh_f,
    const float* __restrict__ bih_f, const float* __restrict__ bhh_f,
    const float* __restrict__ wih_b, const float* __restrict__ whh_b,
    const float* __restrict__ bih_b, const float* __restrict__ bhh_b,
    const float* __restrict__ h0f, const float* __restrict__ h0b,
    char* __restrict__ ws)
{
    int r = blockIdx.x * 256 + threadIdx.x;
    const int n_x = 16777216, n_w = 4194304;
    if (r < n_x) { ((ushort*)(ws + OFF_XB))[r] = f2bf(x[r]); return; }
    r -= n_x;
    if (r < n_w) { ((ushort*)(ws + OFF_WIH_F))[r] = f2bf(wih_f[r]); return; }
    r -= n_w;
    if (r < n_w) { ((ushort*)(ws + OFF_WIH_B))[r] = f2bf(wih_b[r]); return; }
    r -= n_w;
    if (r < n_w) { ((ushort*)(ws + OFF_WHH_F))[r] = f2bf(whh_f[r]); return; }
    r -= n_w;
    if (r < n_w) { ((ushort*)(ws + OFF_WHH_B))[r] = f2bf(whh_b[r]); return; }
    r -= n_w;
    if (r < 4096) { ((float*)(ws + OFF_BSUM_F))[r] = bih_f[r] + bhh_f[r]; return; }
    r -= 4096;
    if (r < 4096) { ((float*)(ws + OFF_BSUM_B))[r] = bih_b[r] + bhh_b[r]; return; }
    r -= 4096;
    if (r < 32768) { ((ushort*)(ws + OFF_HBUF))[r] = f2bf(h0f[r]); return; }             // dir0,parity0
    r -= 32768;
    if (r < 32768) { ((ushort*)(ws + OFF_HBUF))[2 * 32768 + r] = f2bf(h0b[r]); return; } // dir1,parity0
    r -= 32768;
    if (r < 64) { ((uint*)(ws + OFF_FLAGS))[r] = 0u; return; }
}

// ---------------- xg GEMM: xg[slot*32+b][g] = sum_i x[t][b][i] * Wih[g][i] ----------------
__global__ __launch_bounds__(256) void gemm_xg(
    const ushort* __restrict__ xb,
    const ushort* __restrict__ wihf, const ushort* __restrict__ wihb,
    _Float16* __restrict__ xgf, _Float16* __restrict__ xgb,
    int s0)
{
    __shared__ ushort As[128 * 32];
    __shared__ ushort Bs[128 * 32];
    const int dir = blockIdx.z;
    const ushort* __restrict__ W = dir ? wihb : wihf;
    _Float16* __restrict__ xg = dir ? xgb : xgf;
    const int mBlk = blockIdx.x, nBlk = blockIdx.y;
    const int tid = threadIdx.x;
    const int w = tid >> 6, l = tid & 63;
    const int q = l >> 4, ml = l & 15;

    f32x4 acc[4][4];
    const f32x4 zero = {0.f, 0.f, 0.f, 0.f};
#pragma unroll
    for (int i = 0; i < 4; ++i)
#pragma unroll
        for (int j = 0; j < 4; ++j) acc[i][j] = zero;

    for (int kb = 0; kb < 32; ++kb) {
#pragma unroll
        for (int it = 0; it < 2; ++it) {
            int idx = tid + 256 * it;           // 0..511
            int rl = idx >> 2, kc = idx & 3;
            int gr = mBlk * 128 + rl;           // row in slot-space
            int slot = gr >> 5, bb = gr & 31;
            int t = dir ? (511 - s0 - slot) : (s0 + slot);
            const ushort* ga = xb + (size_t)(t * 32 + bb) * 1024 + kb * 32 + kc * 8;
            *(short8*)(As + idx * 8) = *(const short8*)ga;
            int colg = nBlk * 128 + rl;
            const ushort* gbp = W + (size_t)colg * 1024 + kb * 32 + kc * 8;
            *(short8*)(Bs + idx * 8) = *(const short8*)gbp;
        }
        __syncthreads();
        short8 af[4], bfr[4];
#pragma unroll
        for (int i = 0; i < 4; ++i)
            af[i] = *(const short8*)(As + ((w & 1) * 64 + i * 16 + ml) * 32 + q * 8);
#pragma unroll
        for (int j = 0; j < 4; ++j)
            bfr[j] = *(const short8*)(Bs + ((w >> 1) * 64 + j * 16 + ml) * 32 + q * 8);
#pragma unroll
        for (int i = 0; i < 4; ++i)
#pragma unroll
            for (int j = 0; j < 4; ++j)
                acc[i][j] = __builtin_amdgcn_mfma_f32_16x16x32_bf16(af[i], bfr[j], acc[i][j], 0, 0, 0);
        __syncthreads();
    }
#pragma unroll
    for (int i = 0; i < 4; ++i)
#pragma unroll
        for (int j = 0; j < 4; ++j)
#pragma unroll
            for (int rr = 0; rr < 4; ++rr) {
                int row = mBlk * 128 + (w & 1) * 64 + i * 16 + q * 4 + rr;
                int col = nBlk * 128 + (w >> 1) * 64 + j * 16 + ml;
                xg[(size_t)row * 4096 + col] = (_Float16)acc[i][j][rr];
            }
}

// ---------------- recurrence: cooperative, 64 blocks x 512 threads ----------------
// dir = bx&1, p = bx>>1 (0..31). Block owns h-cols [p*32,(p+1)*32). Wave w: gate
// nt=w&3, K-half kh=w>>2; B-frags (32 cols x 512 K) persist in 128 VGPRs/lane.
// ALL inter-block traffic uses RELAXED agent-scope atomics (sc1: write-through /
// L2-bypass). No acquire/release/fence in the loop => no buffer_inv / buffer_wbl2
// cache-maintenance storms (the round-1/2 30us/step killer). Producer ordering:
// write-through h stores -> vmcnt drain (syncthreads) -> relaxed flag post.
__global__ __launch_bounds__(512, 2) void rec_kernel(
    const ushort* __restrict__ whhf, const ushort* __restrict__ whhb,
    const _Float16* __restrict__ xgf, const _Float16* __restrict__ xgb,
    const float* __restrict__ bsumf, const float* __restrict__ bsumb,
    const float* __restrict__ c0f, const float* __restrict__ c0b,
    uint* __restrict__ hbuf, float* __restrict__ cbuf,
    float* __restrict__ out, uint* __restrict__ flags,
    int s0, int csteps)
{
    __shared__ __align__(16) char lds_raw[65536];   // h-stage (64KB), overlaid by gate buf
    ushort* Hst = (ushort*)lds_raw;
    float*  gb  = (float*)lds_raw;

    const int bx = blockIdx.x;
    const int dir = bx & 1;
    const int p = bx >> 1;              // 0..31
    const int tid = threadIdx.x;
    const int w = tid >> 6;             // 0..7
    const int l = tid & 63;
    const int half = l >> 5;
    const int m32 = l & 31;
    const int nt = w & 3;               // gate index
    const int kh = w >> 2;              // K half

    const ushort* W = dir ? whhb : whhf;
    const _Float16* xg = dir ? xgb : xgf;
    const float* bsum = dir ? bsumb : bsumf;
    uint* fl = flags + dir * 32;

    // B-frag preload: col = nt*1024 + p*32 + m32, k = kh*512 + kk*16 + half*8 + j
    const ushort* wrow = W + ((size_t)(nt * 1024 + p * 32 + m32)) * 1024 + kh * 512 + half * 8;
    short8 bfrag[32];
#pragma unroll
    for (int kk = 0; kk < 32; ++kk)
        bfrag[kk] = *(const short8*)(wrow + kk * 16);

    // elementwise identity: thread -> (batch b, col pair rp, rp+1)
    const int b = tid >> 4;             // 0..31
    const int rp = (tid & 15) * 2;      // 0,2,..,30
    const int hcol = p * 32 + rp;
    f32x2 bs[4];
#pragma unroll
    for (int g = 0; g < 4; ++g)
        bs[g] = *(const f32x2*)(bsum + g * 1024 + hcol);
    f32x2 cc;
    {
        const float* csrc = (s0 == 0) ? (dir ? c0b : c0f) : (cbuf + dir * 32768);
        cc = *(const f32x2*)(csrc + b * 1024 + hcol);
    }

    for (int s = s0; s < s0 + csteps; ++s) {
        const int slot = s - s0;
        const int t = dir ? (511 - s) : s;

        // xg for this step: issued first, hidden under flag-wait + staging + MFMA
        uint xv[4];
#pragma unroll
        for (int g = 0; g < 4; ++g)
            xv[g] = *(const uint*)(xg + ((size_t)slot * 32 + b) * 4096 + g * 1024 + hcol);

        // ---- stage h^s (parity s&1) as producers arrive; relaxed polls only ----
        const ull* h64 = (const ull*)(hbuf + (size_t)(dir * 2 + (s & 1)) * 16384);
#pragma unroll
        for (int i = 0; i < 4; ++i) {
            const int pc = w * 4 + i;
            if (l == 0) {
                while (__hip_atomic_load(fl + pc, __ATOMIC_RELAXED, __HIP_MEMORY_SCOPE_AGENT) < (uint)s)
                    __builtin_amdgcn_s_sleep(1);
            }
            asm volatile("" ::: "memory");
#pragma unroll
            for (int uu = 0; uu < 4; ++uu) {
                const int idx = uu * 64 + l;
                const int bb = idx >> 3, uo = idx & 7;
                ull v = __hip_atomic_load(h64 + bb * 256 + pc * 8 + uo,
                                          __ATOMIC_RELAXED, __HIP_MEMORY_SCOPE_AGENT);
                const int ch = pc * 4 + (uo >> 1);
                *(ull*)(Hst + bb * 1024 + ((ch ^ (bb & 7)) << 3) + (uo & 1) * 4) = v;
            }
        }
        __syncthreads();

        // ---- MFMA: gates[32 batch, 32 cols] partial over K-half ----
        f32x16 acce, acco;
#pragma unroll
        for (int i = 0; i < 16; ++i) { acce[i] = 0.f; acco[i] = 0.f; }
#pragma unroll
        for (int kk = 0; kk < 32; kk += 2) {
            const short8 a0 = *(const short8*)(Hst + m32 * 1024 +
                (((kh * 64 + kk * 2 + half) ^ (m32 & 7)) << 3));
            acce = __builtin_amdgcn_mfma_f32_32x32x16_bf16(a0, bfrag[kk], acce, 0, 0, 0);
            const short8 a1 = *(const short8*)(Hst + m32 * 1024 +
                (((kh * 64 + (kk + 1) * 2 + half) ^ (m32 & 7)) << 3));
            acco = __builtin_amdgcn_mfma_f32_32x32x16_bf16(a1, bfrag[kk + 1], acco, 0, 0, 0);
        }
        __syncthreads();   // all Hst reads done before gbuf overlay writes

        // ---- C-store: row=(reg&3)+8*(reg>>2)+4*half, col=m32 ----
#pragma unroll
        for (int reg = 0; reg < 16; ++reg) {
            const int row = (reg & 3) + 8 * (reg >> 2) + 4 * half;
            gb[kh * 4224 + row * 132 + nt * 32 + m32] = acce[reg] + acco[reg];
        }
        __syncthreads();

        // ---- elementwise LSTM update (2 adjacent cols, 1 batch per thread) ----
        const float* gA = gb + b * 132 + rp;
        const float* gB = gb + 4224 + b * 132 + rp;
        f32x2 G[4];
#pragma unroll
        for (int g = 0; g < 4; ++g) {
            h2f xh = __builtin_bit_cast(h2f, xv[g]);
            G[g][0] = gA[g * 32]     + gB[g * 32]     + bs[g][0] + (float)xh[0];
            G[g][1] = gA[g * 32 + 1] + gB[g * 32 + 1] + bs[g][1] + (float)xh[1];
        }
        f32x2 hh;
#pragma unroll
        for (int j = 0; j < 2; ++j) {
            float ii = sigmoidf_(G[0][j]), ff2 = sigmoidf_(G[1][j]);
            float g2 = tanhf(G[2][j]),     oo  = sigmoidf_(G[3][j]);
            cc[j] = ff2 * cc[j] + ii * g2;
            hh[j] = oo * tanhf(cc[j]);
        }
        // write-through h store (packed pair), then drain + barrier + flag post
        uint hp = (uint)f2bf(hh[0]) | ((uint)f2bf(hh[1]) << 16);
        __hip_atomic_store(hbuf + (size_t)(dir * 2 + ((s + 1) & 1)) * 16384 +
                               b * 512 + p * 16 + (tid & 15),
                           hp, __ATOMIC_RELAXED, __HIP_MEMORY_SCOPE_AGENT);
        asm volatile("s_waitcnt vmcnt(0)" ::: "memory");
        __syncthreads();
        if (tid == 0)
            __hip_atomic_store(fl + p, (uint)(s + 1), __ATOMIC_RELAXED, __HIP_MEMORY_SCOPE_AGENT);

        // ---- out stores (off the critical path, nontemporal: keep L2 clean) ----
        __builtin_nontemporal_store(__builtin_bit_cast(double, hh),
            (double*)(out + (size_t)t * 65536 + b * 2048 + dir * 1024 + hcol));
        if (s == 511) {
            float* fin = out + 33554432 + dir * 65536;   // hf,cf then hb,cb
            *(f32x2*)(fin + b * 1024 + hcol) = hh;
            *(f32x2*)(fin + 32768 + b * 1024 + hcol) = cc;
        }
    }
    *(f32x2*)(cbuf + dir * 32768 + b * 1024 + hcol) = cc;
}

// ---------------- host ----------------
extern "C" void kernel_launch(void* const* d_in, const int* in_sizes, int n_in,
                              void* d_out, int out_size, void* d_ws, size_t ws_size,
                              hipStream_t stream)
{
    const float* x     = (const float*)d_in[0];
    const float* h0f   = (const float*)d_in[1];
    const float* c0f   = (const float*)d_in[2];
    const float* h0b   = (const float*)d_in[3];
    const float* c0b   = (const float*)d_in[4];
    const float* wih_f = (const float*)d_in[5];
    const float* whh_f = (const float*)d_in[6];
    const float* bih_f = (const float*)d_in[7];
    const float* bhh_f = (const float*)d_in[8];
    const float* wih_b = (const float*)d_in[9];
    const float* whh_b = (const float*)d_in[10];
    const float* bih_b = (const float*)d_in[11];
    const float* bhh_b = (const float*)d_in[12];
    float* out = (float*)d_out;
    char* ws = (char*)d_ws;

    int csteps = 16;
    const int cands[6] = {512, 256, 128, 64, 32, 16};
    for (int i = 0; i < 6; ++i) {
        size_t need = OFF_XG + 2ull * (size_t)cands[i] * 262144ull;
        if (need <= ws_size) { csteps = cands[i]; break; }
    }

    prep_kernel<<<131361, 256, 0, stream>>>(x, wih_f, whh_f, bih_f, bhh_f,
                                            wih_b, whh_b, bih_b, bhh_b, h0f, h0b, ws);

    const ushort* xb    = (const ushort*)(ws + OFF_XB);
    const ushort* wihfb = (const ushort*)(ws + OFF_WIH_F);
    const ushort* wihbb = (const ushort*)(ws + OFF_WIH_B);
    const ushort* whhfb = (const ushort*)(ws + OFF_WHH_F);
    const ushort* whhbb = (const ushort*)(ws + OFF_WHH_B);
    const float*  bsf   = (const float*)(ws + OFF_BSUM_F);
    const float*  bsb   = (const float*)(ws + OFF_BSUM_B);
    uint*   hb          = (uint*)(ws + OFF_HBUF);
    float*  cb          = (float*)(ws + OFF_CBUF);
    uint*   flagsp      = (uint*)(ws + OFF_FLAGS);
    _Float16* xgfp      = (_Float16*)(ws + OFF_XG);
    _Float16* xgbp      = (_Float16*)(ws + OFF_XG + (size_t)csteps * 262144ull);

    const int nchunks = 512 / csteps;
    for (int cidx = 0; cidx < nchunks; ++cidx) {
        int s0 = cidx * csteps;
        gemm_xg<<<dim3(csteps / 4, 32, 2), 256, 0, stream>>>(xb, wihfb, wihbb, xgfp, xgbp, s0);

        const ushort* a0 = whhfb; const ushort* a1 = whhbb;
        const _Float16* a2 = xgfp; const _Float16* a3 = xgbp;
        const float* a4 = bsf; const float* a5 = bsb;
        const float* a6 = c0f; const float* a7 = c0b;
        uint* a8 = hb; float* a9 = cb; float* a10 = out; uint* a11 = flagsp;
        int a12 = s0, a13 = csteps;
        void* args[] = {&a0, &a1, &a2, &a3, &a4, &a5, &a6, &a7, &a8, &a9, &a10, &a11, &a12, &a13};
        hipLaunchCooperativeKernel((void*)rec_kernel, dim3(64), dim3(512), args, 0, stream);
    }
}